// Round 14
// baseline (300.606 us; speedup 1.0000x reference)
//
#include <hip/hip_runtime.h>
#include <hip/hip_bf16.h>
#include <hip/hip_fp16.h>

typedef _Float16 half8 __attribute__((ext_vector_type(8)));
typedef _Float16 half4 __attribute__((ext_vector_type(4)));
typedef float f32x4 __attribute__((ext_vector_type(4)));
typedef unsigned int u32;

#define S_LEN 2048
#define HID_DIM 4096
#define N_HEADS 32
#define N_KV 8
#define HEAD_DIM 128
#define SCALE_QK 0.08838834764831845f

// ---------- async global->LDS (16B per lane, wave-uniform LDS base) ----------
__device__ __forceinline__ void async16(void* lds, const void* gptr) {
  __builtin_amdgcn_global_load_lds(
      (const __attribute__((address_space(1))) u32*)gptr,
      (__attribute__((address_space(3))) u32*)lds, 16, 0, 0);
}

#define PIN() __builtin_amdgcn_sched_barrier(0)

// ---------- 64x64 transpose tile body (f32 [R][C] -> f16 [C][R]) ----------
__device__ __forceinline__ void transpose_tile(const float* __restrict__ src,
                                               _Float16* __restrict__ dst, int R, int C,
                                               int bx, int by, float (*tile)[73], int t) {
  {
    const int c4 = (t & 15) * 4;
    const int r0 = t >> 4;  // 0..15
#pragma unroll
    for (int i = 0; i < 4; i++) {
      int r = r0 + 16 * i;
      float4 v = *(const float4*)&src[(long)(by * 64 + r) * C + bx * 64 + c4];
      tile[r][c4] = v.x; tile[r][c4 + 1] = v.y; tile[r][c4 + 2] = v.z; tile[r][c4 + 3] = v.w;
    }
  }
  __syncthreads();
  const int kc = t & 7;
  const int n0 = t >> 3;  // 0..31
#pragma unroll
  for (int p = 0; p < 2; p++) {
    int n = n0 + 32 * p;
    half8 o;
#pragma unroll
    for (int j = 0; j < 8; j++) o[j] = (_Float16)tile[kc * 8 + j][n];
    *(half8*)&dst[(long)(bx * 64 + n) * R + by * 64 + kc * 8] = o;
  }
}

// ---------- merged prep: X conversion + wq^T + wk^T + wv^T in ONE dispatch ----------
__global__ void prep_kernel(const float* __restrict__ x, _Float16* __restrict__ Xh,
                            const float* __restrict__ wq, _Float16* __restrict__ WqT,
                            const float* __restrict__ wk, const float* __restrict__ wv,
                            _Float16* __restrict__ WkvT) {
  __shared__ float tile[64][73];
  const int bid = blockIdx.x;
  const int t = threadIdx.x;
  if (bid < 4096) {  // conv: 4096*256 == S*HID/8 exactly
    int i = bid * 256 + t;
    float4 a = ((const float4*)x)[2 * i];
    float4 b = ((const float4*)x)[2 * i + 1];
    half8 h;
    h[0] = (_Float16)a.x; h[1] = (_Float16)a.y; h[2] = (_Float16)a.z; h[3] = (_Float16)a.w;
    h[4] = (_Float16)b.x; h[5] = (_Float16)b.y; h[6] = (_Float16)b.z; h[7] = (_Float16)b.w;
    ((half8*)Xh)[i] = h;
  } else if (bid < 8192) {  // wq^T
    int tt = bid - 4096;
    transpose_tile(wq, WqT, 4096, 4096, tt & 63, tt >> 6, tile, t);
  } else if (bid < 9216) {  // wk^T
    int tt = bid - 8192;
    transpose_tile(wk, WkvT, 4096, 1024, tt & 15, tt >> 4, tile, t);
  } else {  // wv^T
    int tt = bid - 9216;
    transpose_tile(wv, WkvT + (size_t)1024 * 4096, 4096, 1024, tt & 15, tt >> 4, tile, t);
  }
}

// ---------- 8-phase 256x256 QKV GEMM (m201 template): [2048][4096] @ [6144][4096]^T ----
// 512 thr = 8 waves (2M x 4N); BK=64; LDS = 2 slots x (A 32K + B 32K) = 128KB.
// st_16x32 swizzle: LDS dest linear, global SOURCE pre-swizzled, ds_read swizzled.
// Counted vmcnt(2) at tile boundaries (T4); setprio around MFMA clusters (T5).
// Epilogues: Q frag-tiled pre-rope; K frag-tiled + fused RoPE (wn<->wn^1 exchange
// via LDS overlay after final drain); V PV-fragment layout.
__global__ __launch_bounds__(512, 2) void gemm_qkv8(
    const _Float16* __restrict__ A, const _Float16* __restrict__ BtQ,
    const _Float16* __restrict__ BtKV, _Float16* __restrict__ Qt,
    _Float16* __restrict__ Kt, _Float16* __restrict__ Vt,
    const float* __restrict__ cosb, const float* __restrict__ sinb) {
  __shared__ __align__(16) char smem[131072];  // As [0,64K), Bs [64K,128K)
  const int K = 4096;
  const int NT = 64;  // K/64
  const int tid = threadIdx.x, lane = tid & 63, w = tid >> 6;
  const int row0 = blockIdx.y * 256;
  const int col0 = blockIdx.x * 256;
  const int wm = w >> 2, wn = w & 3;
  const int lr = lane & 15, lg = lane >> 4;

  const _Float16* bbase = (col0 < 4096) ? (BtQ + (long)col0 * K)
                                        : (BtKV + (long)(col0 - 4096) * K);
  // staging: lane l -> subtile row l>>3, source chunk pre-swizzled (involution)
  const int srow = lane >> 3;
  const int schunk = (lane & 7) ^ ((lane & 32) ? 2 : 0);
  const _Float16* aS0 = A + (long)(row0 + (2 * w) * 8 + srow) * K + schunk * 8;
  const _Float16* aS1 = A + (long)(row0 + (2 * w + 1) * 8 + srow) * K + schunk * 8;
  const _Float16* bS0 = bbase + (long)((2 * w) * 8 + srow) * K + schunk * 8;
  const _Float16* bS1 = bbase + (long)((2 * w + 1) * 8 + srow) * K + schunk * 8;
  char* AsB = smem;
  char* BsB = smem + 65536;
  const long HSTEP = (long)128 * K;  // half stride in source rows

  // stage half h of K-tile t into slot sl (2 wave-instrs; dest linear)
#define STG_A(sl, h, t) do { \
    async16(AsB + (sl) * 32768 + (h) * 16384 + (2 * w) * 1024,     aS0 + (h) * HSTEP + (t) * 64); \
    async16(AsB + (sl) * 32768 + (h) * 16384 + (2 * w + 1) * 1024, aS1 + (h) * HSTEP + (t) * 64); \
  } while (0)
#define STG_B(sl, h, t) do { \
    async16(BsB + (sl) * 32768 + (h) * 16384 + (2 * w) * 1024,     bS0 + (h) * HSTEP + (t) * 64); \
    async16(BsB + (sl) * 32768 + (h) * 16384 + (2 * w + 1) * 1024, bS1 + (h) * HSTEP + (t) * 64); \
  } while (0)

  // fragment read bases (f16 units); swizzled chunk per kk
  const int cs0 = ((0 + lg) ^ ((lr & 4) ? 2 : 0)) * 8;  // kk=0: chunk lg
  const int cs1 = ((4 + lg) ^ ((lr & 4) ? 2 : 0)) * 8;  // kk=1: chunk 4+lg
  const _Float16* Af = (const _Float16*)AsB + wm * 8192 + lr * 64;
  const _Float16* Bf = (const _Float16*)BsB + (wn >> 1) * 8192 + ((wn & 1) * 64 + lr) * 64;

  f32x4 acc[8][4] = {};

  // prologue: tile0 (4 halves) + Ah0 of tile1; counted wait (tile0 retired, 2 in flight)
  STG_A(0, 0, 0); STG_A(0, 1, 0); STG_B(0, 0, 0); STG_B(0, 1, 0);
  STG_A(1, 0, 1);
  asm volatile("s_waitcnt vmcnt(2)" ::: "memory");
  PIN(); __builtin_amdgcn_s_barrier(); PIN();

  for (int t = 0; t < NT; ++t) {
    const int sl = t & 1;
    const int so = sl * 16384;
    half8 bf[4], af[4];

    // ---- phase 1: q0,kk0 (read B kk0) | stage Ah1(t+1)
#pragma unroll
    for (int nf = 0; nf < 4; nf++) bf[nf] = *(const half8*)(Bf + so + nf * 1024 + cs0);
#pragma unroll
    for (int m = 0; m < 4; m++) af[m] = *(const half8*)(Af + so + m * 1024 + cs0);
    if (t + 1 < NT) STG_A(sl ^ 1, 1, t + 1);
    PIN(); __builtin_amdgcn_s_barrier(); PIN();
    __builtin_amdgcn_s_setprio(1);
#pragma unroll
    for (int m = 0; m < 4; m++)
#pragma unroll
      for (int nf = 0; nf < 4; nf++)
        acc[m][nf] = __builtin_amdgcn_mfma_f32_16x16x32_f16(af[m], bf[nf], acc[m][nf], 0, 0, 0);
    __builtin_amdgcn_s_setprio(0);
    PIN(); __builtin_amdgcn_s_barrier(); PIN();

    // ---- phase 2: q1,kk0 (reuse B) | stage Bh0(t+1)
#pragma unroll
    for (int m = 0; m < 4; m++) af[m] = *(const half8*)(Af + so + (4 + m) * 1024 + cs0);
    if (t + 1 < NT) STG_B(sl ^ 1, 0, t + 1);
    PIN(); __builtin_amdgcn_s_barrier(); PIN();
    __builtin_amdgcn_s_setprio(1);
#pragma unroll
    for (int m = 0; m < 4; m++)
#pragma unroll
      for (int nf = 0; nf < 4; nf++)
        acc[4 + m][nf] = __builtin_amdgcn_mfma_f32_16x16x32_f16(af[m], bf[nf], acc[4 + m][nf], 0, 0, 0);
    __builtin_amdgcn_s_setprio(0);
    PIN(); __builtin_amdgcn_s_barrier(); PIN();

    // ---- phase 3: q0,kk1 (read B kk1) | stage Bh1(t+1)
#pragma unroll
    for (int nf = 0; nf < 4; nf++) bf[nf] = *(const half8*)(Bf + so + nf * 1024 + cs1);
#pragma unroll
    for (int m = 0; m < 4; m++) af[m] = *(const half8*)(Af + so + m * 1024 + cs1);
    if (t + 1 < NT) STG_B(sl ^ 1, 1, t + 1);
    PIN(); __builtin_amdgcn_s_barrier(); PIN();
    __builtin_amdgcn_s_setprio(1);
#pragma unroll
    for (int m = 0; m < 4; m++)
#pragma unroll
      for (int nf = 0; nf < 4; nf++)
        acc[m][nf] = __builtin_amdgcn_mfma_f32_16x16x32_f16(af[m], bf[nf], acc[m][nf], 0, 0, 0);
    __builtin_amdgcn_s_setprio(0);
    PIN(); __builtin_amdgcn_s_barrier(); PIN();

    // ---- phase 4: q1,kk1
#pragma unroll
    for (int m = 0; m < 4; m++) af[m] = *(const half8*)(Af + so + (4 + m) * 1024 + cs1);
    PIN(); __builtin_amdgcn_s_barrier(); PIN();
    __builtin_amdgcn_s_setprio(1);
#pragma unroll
    for (int m = 0; m < 4; m++)
#pragma unroll
      for (int nf = 0; nf < 4; nf++)
        acc[4 + m][nf] = __builtin_amdgcn_mfma_f32_16x16x32_f16(af[m], bf[nf], acc[4 + m][nf], 0, 0, 0);
    __builtin_amdgcn_s_setprio(0);
    // boundary: all waves done reading slot sl after this barrier
    PIN(); __builtin_amdgcn_s_barrier(); PIN();
    if (t + 2 < NT) {
      STG_A(sl, 0, t + 2);  // slot sl just freed
      asm volatile("s_waitcnt vmcnt(2)" ::: "memory");  // t+1 halves retired, t+2 in flight
    } else if (t + 1 < NT) {
      asm volatile("s_waitcnt vmcnt(0)" ::: "memory");  // final handoff only
    }
    PIN(); __builtin_amdgcn_s_barrier(); PIN();
  }

  // ---------------- epilogue (all staging drained) ----------------
  if (col0 < 4096) {  // Q frag-tiled (pre-rope)
#pragma unroll
    for (int mf = 0; mf < 8; mf++)
#pragma unroll
      for (int nf = 0; nf < 4; nf++) {
        int rbase = row0 + wm * 128 + mf * 16 + lg * 4;
        int col = col0 + wn * 64 + nf * 16 + lr;
        int h = col >> 7, d = col & 127;
        long off = ((long)((h * 128 + (rbase >> 4)) * 4 + (d >> 5))) * 512 +
                   ((d >> 3) & 3) * 128 + (rbase & 15) * 8 + (d & 7);
#pragma unroll
        for (int i = 0; i < 4; i++) Qt[off + i * 8] = (_Float16)acc[mf][nf][i];
      }
  } else if (col0 < 5120) {  // K frag-tiled + fused RoPE (wn pair exchange via overlay)
    float* fl = (float*)smem;
    float* myreg = fl + (wm * 2 + (wn >> 1)) * 8192;  // [128][64] f32
    if (wn & 1) {  // hi half (d in [64,128)): stash
#pragma unroll
      for (int mf = 0; mf < 8; mf++)
#pragma unroll
        for (int nf = 0; nf < 4; nf++)
#pragma unroll
          for (int i = 0; i < 4; i++)
            myreg[(mf * 16 + lg * 4 + i) * 64 + nf * 16 + lr] = acc[mf][nf][i];
    }
    __syncthreads();
    if (!(wn & 1)) {  // lo half: write both halves roped
      const int g = ((col0 - 4096) >> 7) + (wn >> 1);
#pragma unroll
      for (int mf = 0; mf < 8; mf++)
#pragma unroll
        for (int nf = 0; nf < 4; nf++)
#pragma unroll
          for (int i = 0; i < 4; i++) {
            int rl = mf * 16 + lg * 4 + i;
            int d = nf * 16 + lr;
            int s_glob = row0 + wm * 128 + rl;
            float lo = acc[mf][nf][i];
            float hi = myreg[rl * 64 + d];
            float c = cosb[s_glob * 128 + d];
            float sn = sinb[s_glob * 128 + d];
            long off = ((long)((g * 128 + (s_glob >> 4)) * 4 + (d >> 5))) * 512 +
                       ((d >> 3) & 3) * 128 + (s_glob & 15) * 8 + (d & 7);
            Kt[off] = (_Float16)(lo * c - hi * sn);
            Kt[off + 1024] = (_Float16)(hi * c + lo * sn);
          }
    }
  } else {  // V PV-fragment layout
#pragma unroll
    for (int mf = 0; mf < 8; mf++)
#pragma unroll
      for (int nf = 0; nf < 4; nf++) {
        int rbase = row0 + wm * 128 + mf * 16 + lg * 4;
        int col = col0 + wn * 64 + nf * 16 + lr;
        int gc = col - 5120;
        int gq = gc >> 7, d = gc & 127;
        int dt = d >> 4, lrr = d & 15;
        int kvb = rbase >> 5, lgv = (rbase >> 3) & 3, j = rbase & 7;
        half4 v;
#pragma unroll
        for (int i = 0; i < 4; i++) v[i] = (_Float16)acc[mf][nf][i];
        long off = ((long)(gq * 64 + kvb) * 8 + dt) * 512 + (lgv * 16 + lrr) * 8 + j;
        *(half4*)&Vt[off] = v;
      }
  }
#undef STG_A
#undef STG_B
}

// ---------- O-projection GEMM: [2048][4096] f16 @ [4096][4096]^T -> f32 out ----------
__global__ __launch_bounds__(256, 3) void gemm_out(
    const _Float16* __restrict__ A, const _Float16* __restrict__ Bt,
    float* __restrict__ C) {
  __shared__ _Float16 As[128 * 64];
  __shared__ _Float16 Bs[128 * 64];
  const int K = 4096;
  const int tid = threadIdx.x, lane = tid & 63, wid = tid >> 6;
  const int row0 = blockIdx.y * 128;
  const int col0 = blockIdx.x * 128;
  const int wm = wid >> 1, wn = wid & 1;
  const int lr = lane & 15, lg = lane >> 4;

  const int scol = ((lane & 7) ^ ((lane >> 3) & 7)) * 8;
  const _Float16* aptr = A + (long)(row0 + wid * 32 + (lane >> 3)) * K + scol;
  const _Float16* bptr = Bt + (long)(col0 + wid * 32 + (lane >> 3)) * K + scol;
  _Float16* alds = As + (wid * 4) * 512;
  _Float16* blds = Bs + (wid * 4) * 512;

  f32x4 acc[4][4] = {};
  for (int k0 = 0; k0 < K; k0 += 64) {
#pragma unroll
    for (int j = 0; j < 4; j++) {
      async16(alds + j * 512, aptr + k0 + (long)j * 8 * K);
      async16(blds + j * 512, bptr + k0 + (long)j * 8 * K);
    }
    __syncthreads();
    half8 a[2][4], b[2][4];
#pragma unroll
    for (int kk = 0; kk < 2; kk++)
#pragma unroll
      for (int mf = 0; mf < 4; mf++) {
        a[kk][mf] = *(const half8*)&As[(wm * 64 + mf * 16 + lr) * 64 +
                                       (((kk * 4 + lg) ^ (lr & 7)) * 8)];
        b[kk][mf] = *(const half8*)&Bs[(wn * 64 + mf * 16 + lr) * 64 +
                                       (((kk * 4 + lg) ^ (lr & 7)) * 8)];
      }
#pragma unroll
    for (int kk = 0; kk < 2; kk++)
#pragma unroll
      for (int mf = 0; mf < 4; mf++)
#pragma unroll
        for (int nf = 0; nf < 4; nf++)
          acc[mf][nf] =
              __builtin_amdgcn_mfma_f32_16x16x32_f16(a[kk][mf], b[kk][nf], acc[mf][nf], 0, 0, 0);
    __syncthreads();
  }
#pragma unroll
  for (int mf = 0; mf < 4; mf++)
#pragma unroll
    for (int nf = 0; nf < 4; nf++) {
      int rbase = row0 + wm * 64 + mf * 16 + lg * 4;
      int col = col0 + wn * 64 + nf * 16 + lr;
#pragma unroll
      for (int i = 0; i < 4; i++)
        C[(long)(rbase + i) * 4096 + col] = acc[mf][nf][i];
    }
}

// ---------- fused: causal GQA attention (bid<1024) + wo^T transpose (bid>=1024) ----------
// (256,3): do NOT tighten to (256,4) — R12 showed spills (attn 57 -> 112us).
__global__ __launch_bounds__(256, 3) void attn_wo_kernel(
    const _Float16* __restrict__ Qt, const _Float16* __restrict__ Kt,
    const _Float16* __restrict__ Vt, _Float16* __restrict__ O,
    const float* __restrict__ cosb, const float* __restrict__ sinb,
    const float* __restrict__ wo, _Float16* __restrict__ WoT) {
  __shared__ __align__(16) char smem[36864];
  const int tid = threadIdx.x;
  const int bid = blockIdx.x;  // 1024 attn + 4096 transpose

  if (bid >= 1024) {  // ---- wo^T
    int tt = bid - 1024;
    transpose_tile(wo, WoT, 4096, 4096, tt & 63, tt >> 6, (float(*)[73])smem, tid);
    return;
  }

  _Float16* Kb = (_Float16*)smem;            // [2][4096]
  _Float16* Vb = (_Float16*)(smem + 16384);  // [2][4096]
  _Float16* Pb = (_Float16*)(smem + 32768) + (tid >> 6) * 512;  // per-wave [512]

  const int lane = tid & 63;
  const int wid = tid >> 6;
  const int g = bid & 7;
  const int qidx = bid >> 3;
  const int qt16 = (qidx < 64) ? (2 * qidx) : (2 * (127 - qidx) + 1);
  const int h = g * 4 + wid;
  const int qrow0 = qt16 * 16;
  const int ntiles = (qrow0 + 47) >> 5;
  const int lr = lane & 15;
  const int lg = lane >> 4;

  // Q fragments + fused RoPE (rotate-half partner: fragment t <-> t+2, same lane)
  half8 qf[4];
  {
    const _Float16* qp = Qt + ((long)(h * 128 + qt16) * 4) * 512 + lane * 8;
#pragma unroll
    for (int t = 0; t < 4; t++) qf[t] = *(const half8*)(qp + t * 512);
    int s = qrow0 + lr;
#pragma unroll
    for (int t = 0; t < 2; t++) {
      const float* cp = cosb + s * 128 + t * 32 + lg * 8;
      const float* sp = sinb + s * 128 + t * 32 + lg * 8;
#pragma unroll
      for (int j = 0; j < 8; j++) {
        float c = cp[j], sn = sp[j];
        float lo = (float)qf[t][j], hi = (float)qf[t + 2][j];
        qf[t][j]     = (_Float16)(lo * c - hi * sn);
        qf[t + 2][j] = (_Float16)(hi * c + lo * sn);
      }
    }
  }

  const _Float16* kgb = Kt + (long)g * 128 * 2048 + lane * 8;
  const _Float16* vgb = Vt + (long)g * 64 * 4096 + lane * 8;

  {
    async16(&Kb[(2 * wid) * 512], kgb + (2 * wid) * 512);
    async16(&Kb[(2 * wid + 1) * 512], kgb + (2 * wid + 1) * 512);
    async16(&Vb[(2 * wid) * 512], vgb + (2 * wid) * 512);
    async16(&Vb[(2 * wid + 1) * 512], vgb + (2 * wid + 1) * 512);
  }
  __syncthreads();

  f32x4 oacc[8] = {};
  float mrow[4] = {-1e30f, -1e30f, -1e30f, -1e30f};
  float lsum[4] = {0.f, 0.f, 0.f, 0.f};

  for (int t = 0; t < ntiles; t++) {
    const int kb = t * 32;
    const int cur = t & 1;
    if (t + 1 < ntiles) {
      const _Float16* ks = kgb + (long)(t + 1) * 4096;
      const _Float16* vs = vgb + (long)(t + 1) * 4096;
      async16(&Kb[(cur ^ 1) * 4096 + (2 * wid) * 512], ks + (2 * wid) * 512);
      async16(&Kb[(cur ^ 1) * 4096 + (2 * wid + 1) * 512], ks + (2 * wid + 1) * 512);
      async16(&Vb[(cur ^ 1) * 4096 + (2 * wid) * 512], vs + (2 * wid) * 512);
      async16(&Vb[(cur ^ 1) * 4096 + (2 * wid + 1) * 512], vs + (2 * wid + 1) * 512);
    }

    half8 kf[8];
#pragma unroll
    for (int c = 0; c < 8; c++)
      kf[c] = *(const half8*)&Kb[cur * 4096 + c * 512 + lane * 8];
    half8 vf[8];
#pragma unroll
    for (int dt = 0; dt < 8; dt++)
      vf[dt] = *(const half8*)&Vb[cur * 4096 + dt * 512 + lane * 8];

    f32x4 sacc[2] = {};
    __builtin_amdgcn_s_setprio(1);
#pragma unroll
    for (int s = 0; s < 2; s++)
#pragma unroll
      for (int t2 = 0; t2 < 4; t2++)
        sacc[s] = __builtin_amdgcn_mfma_f32_16x16x32_f16(qf[t2], kf[s * 4 + t2], sacc[s], 0, 0, 0);
    __builtin_amdgcn_s_setprio(0);

#pragma unroll
    for (int i = 0; i < 4; i++) {
      sacc[0][i] *= SCALE_QK;
      sacc[1][i] *= SCALE_QK;
    }
    if (t == ntiles - 1) {  // only the last tile can touch the diagonal
#pragma unroll
      for (int i = 0; i < 4; i++) {
        int qrow = qrow0 + lg * 4 + i;
        if (kb + lr > qrow) sacc[0][i] = -1e30f;
        if (kb + 16 + lr > qrow) sacc[1][i] = -1e30f;
      }
    }
    float mx[4];
    bool grow = false;
#pragma unroll
    for (int i = 0; i < 4; i++) {
      mx[i] = fmaxf(sacc[0][i], sacc[1][i]);
      grow |= (mx[i] > mrow[i] + 4.0f);
    }
    if (__any((int)grow)) {
#pragma unroll
      for (int i = 0; i < 4; i++) {
        float m = mx[i];
        m = fmaxf(m, __shfl_xor(m, 1));
        m = fmaxf(m, __shfl_xor(m, 2));
        m = fmaxf(m, __shfl_xor(m, 4));
        m = fmaxf(m, __shfl_xor(m, 8));
        float mn = fmaxf(mrow[i], m);
        float scl = __expf(mrow[i] - mn);
        mrow[i] = mn;
        lsum[i] *= scl;
#pragma unroll
        for (int dt = 0; dt < 8; dt++) oacc[dt][i] *= scl;
      }
    }
    float p[2][4];
#pragma unroll
    for (int i = 0; i < 4; i++) {
      p[0][i] = __expf(sacc[0][i] - mrow[i]);
      p[1][i] = __expf(sacc[1][i] - mrow[i]);
      lsum[i] += p[0][i] + p[1][i];
    }

#pragma unroll
    for (int sub = 0; sub < 2; sub++)
#pragma unroll
      for (int i = 0; i < 4; i++)
        Pb[(lg * 4 + i) * 32 + sub * 16 + lr] = (_Float16)p[sub][i];
    half8 pa = *(const half8*)&Pb[lr * 32 + lg * 8];

    __builtin_amdgcn_s_setprio(1);
#pragma unroll
    for (int dt = 0; dt < 8; dt++)
      oacc[dt] = __builtin_amdgcn_mfma_f32_16x16x32_f16(pa, vf[dt], oacc[dt], 0, 0, 0);
    __builtin_amdgcn_s_setprio(0);

    __syncthreads();
  }

#pragma unroll
  for (int i = 0; i < 4; i++) {
    float t2 = lsum[i];
    t2 += __shfl_xor(t2, 1);
    t2 += __shfl_xor(t2, 2);
    t2 += __shfl_xor(t2, 4);
    t2 += __shfl_xor(t2, 8);
    lsum[i] = t2;
  }
#pragma unroll
  for (int dt = 0; dt < 8; dt++) {
#pragma unroll
    for (int i = 0; i < 4; i++) {
      float o = oacc[dt][i] / lsum[i];
      O[(long)(qrow0 + lg * 4 + i) * HID_DIM + h * HEAD_DIM + dt * 16 + lr] = (_Float16)o;
    }
  }
}

extern "C" void kernel_launch(void* const* d_in, const int* in_sizes, int n_in,
                              void* d_out, int out_size, void* d_ws, size_t ws_size,
                              hipStream_t stream) {
  const float* x    = (const float*)d_in[0];
  const float* cosb = (const float*)d_in[1];
  const float* sinb = (const float*)d_in[2];
  // d_in[3] = attn_mask: pure causal, implemented in-kernel
  const float* wq = (const float*)d_in[4];
  const float* wk = (const float*)d_in[5];
  const float* wv = (const float*)d_in[6];
  const float* wo = (const float*)d_in[7];
  float* out = (float*)d_out;

  char* ws = (char*)d_ws;
  _Float16* Xh    = (_Float16*)(ws);                        // [0,16M): X f16; later Oattn
  _Float16* Oattn = Xh;
  _Float16* Qt    = (_Float16*)(ws + (size_t)(16 << 20));   // [16,32M): Q frag-tiled (pre-rope)
  _Float16* Kt    = (_Float16*)(ws + (size_t)(32 << 20));   // [32,36M): K frag-tiled (roped)
  _Float16* Vt    = (_Float16*)(ws + (size_t)(36 << 20));   // [36,40M): V PV-tiled
  _Float16* WqT   = (_Float16*)(ws + (size_t)(40 << 20));   // [40,72M): wq^T, later wo^T
  _Float16* WoT   = WqT;
  _Float16* WkvT  = (_Float16*)d_out;                       // 16MB scratch in d_out
  // peak ws usage: 72 MiB

  dim3 b256(256);

  // merged prep: X->f16 + wq^T + wk^T + wv^T (one dispatch, 10240 blocks)
  prep_kernel<<<dim3(10240), b256, 0, stream>>>(x, Xh, wq, WqT, wk, wv, WkvT);

  // 8-phase 256^2 QKV projection (N=6144: 24x8 = 192 blocks, 1/CU), fused K-RoPE
  gemm_qkv8<<<dim3(6144 / 256, S_LEN / 256), dim3(512), 0, stream>>>(
      Xh, WqT, WkvT, Qt, Kt, Vt, cosb, sinb);

  // fused: causal GQA attention (+Q-RoPE) -> Oattn, with wo^T hidden underneath
  attn_wo_kernel<<<dim3(1024 + 4096), b256, 0, stream>>>(Qt, Kt, Vt, Oattn, cosb, sinb, wo, WoT);

  // out = Oattn @ Wo (f32)
  gemm_out<<<dim3(4096 / 128, S_LEN / 128), b256, 0, stream>>>(Oattn, WoT, out);
}

// Round 15
// 289.590 us; speedup vs baseline: 1.0380x; 1.0380x over previous
//
#include <hip/hip_runtime.h>
#include <hip/hip_bf16.h>
#include <hip/hip_fp16.h>

typedef _Float16 half8 __attribute__((ext_vector_type(8)));
typedef _Float16 half4 __attribute__((ext_vector_type(4)));
typedef float f32x4 __attribute__((ext_vector_type(4)));
typedef unsigned int u32;

#define S_LEN 2048
#define HID_DIM 4096
#define N_HEADS 32
#define N_KV 8
#define HEAD_DIM 128
#define SCALE_QK 0.08838834764831845f

// ---------- async global->LDS (16B per lane, wave-uniform LDS base) ----------
__device__ __forceinline__ void async16(void* lds, const void* gptr) {
  __builtin_amdgcn_global_load_lds(
      (const __attribute__((address_space(1))) u32*)gptr,
      (__attribute__((address_space(3))) u32*)lds, 16, 0, 0);
}

#define PIN() __builtin_amdgcn_sched_barrier(0)

// ---------- 64x64 transpose tile body (f32 [R][C] -> f16 [C][R]) ----------
__device__ __forceinline__ void transpose_tile(const float* __restrict__ src,
                                               _Float16* __restrict__ dst, int R, int C,
                                               int bx, int by, float (*tile)[73], int t) {
  {
    const int c4 = (t & 15) * 4;
    const int r0 = t >> 4;  // 0..15
#pragma unroll
    for (int i = 0; i < 4; i++) {
      int r = r0 + 16 * i;
      float4 v = *(const float4*)&src[(long)(by * 64 + r) * C + bx * 64 + c4];
      tile[r][c4] = v.x; tile[r][c4 + 1] = v.y; tile[r][c4 + 2] = v.z; tile[r][c4 + 3] = v.w;
    }
  }
  __syncthreads();
  const int kc = t & 7;
  const int n0 = t >> 3;  // 0..31
#pragma unroll
  for (int p = 0; p < 2; p++) {
    int n = n0 + 32 * p;
    half8 o;
#pragma unroll
    for (int j = 0; j < 8; j++) o[j] = (_Float16)tile[kc * 8 + j][n];
    *(half8*)&dst[(long)(bx * 64 + n) * R + by * 64 + kc * 8] = o;
  }
}

// ---------- merged prep: X conversion + wq^T + wk^T + wv^T in ONE dispatch ----------
__global__ void prep_kernel(const float* __restrict__ x, _Float16* __restrict__ Xh,
                            const float* __restrict__ wq, _Float16* __restrict__ WqT,
                            const float* __restrict__ wk, const float* __restrict__ wv,
                            _Float16* __restrict__ WkvT) {
  __shared__ float tile[64][73];
  const int bid = blockIdx.x;
  const int t = threadIdx.x;
  if (bid < 4096) {  // conv: 4096*256 == S*HID/8 exactly
    int i = bid * 256 + t;
    float4 a = ((const float4*)x)[2 * i];
    float4 b = ((const float4*)x)[2 * i + 1];
    half8 h;
    h[0] = (_Float16)a.x; h[1] = (_Float16)a.y; h[2] = (_Float16)a.z; h[3] = (_Float16)a.w;
    h[4] = (_Float16)b.x; h[5] = (_Float16)b.y; h[6] = (_Float16)b.z; h[7] = (_Float16)b.w;
    ((half8*)Xh)[i] = h;
  } else if (bid < 8192) {  // wq^T
    int tt = bid - 4096;
    transpose_tile(wq, WqT, 4096, 4096, tt & 63, tt >> 6, tile, t);
  } else if (bid < 9216) {  // wk^T
    int tt = bid - 8192;
    transpose_tile(wk, WkvT, 4096, 1024, tt & 15, tt >> 4, tile, t);
  } else {  // wv^T
    int tt = bid - 9216;
    transpose_tile(wv, WkvT + (size_t)1024 * 4096, 4096, 1024, tt & 15, tt >> 4, tile, t);
  }
}

// ---------- 8-phase 256x256 QKV GEMM (m201 template): [2048][4096] @ [6144][4096]^T ----
// Swizzle fixed vs R14: full 3-bit involution (chunk ^ row&7), matching the proven
// 0-conflict 2-phase formula. Source pre-swizzled, LDS dest linear, ds_read swizzled.
__global__ __launch_bounds__(512, 2) void gemm_qkv8(
    const _Float16* __restrict__ A, const _Float16* __restrict__ BtQ,
    const _Float16* __restrict__ BtKV, _Float16* __restrict__ Qt,
    _Float16* __restrict__ Kt, _Float16* __restrict__ Vt,
    const float* __restrict__ cosb, const float* __restrict__ sinb) {
  __shared__ __align__(16) char smem[131072];  // As [0,64K), Bs [64K,128K)
  const int K = 4096;
  const int NT = 64;  // K/64
  const int tid = threadIdx.x, lane = tid & 63, w = tid >> 6;
  const int row0 = blockIdx.y * 256;
  const int col0 = blockIdx.x * 256;
  const int wm = w >> 2, wn = w & 3;
  const int lr = lane & 15, lg = lane >> 4;

  const _Float16* bbase = (col0 < 4096) ? (BtQ + (long)col0 * K)
                                        : (BtKV + (long)(col0 - 4096) * K);
  // staging: lane l -> subtile row l>>3, chunk l&7; SOURCE chunk = (l&7) ^ (l>>3)
  const int srow = lane >> 3;
  const int schunk = (lane & 7) ^ srow;
  const _Float16* aS0 = A + (long)(row0 + (2 * w) * 8 + srow) * K + schunk * 8;
  const _Float16* aS1 = A + (long)(row0 + (2 * w + 1) * 8 + srow) * K + schunk * 8;
  const _Float16* bS0 = bbase + (long)((2 * w) * 8 + srow) * K + schunk * 8;
  const _Float16* bS1 = bbase + (long)((2 * w + 1) * 8 + srow) * K + schunk * 8;
  char* AsB = smem;
  char* BsB = smem + 65536;
  const long HSTEP = (long)128 * K;  // half stride in source rows

#define STG_A(sl, h, t) do { \
    async16(AsB + (sl) * 32768 + (h) * 16384 + (2 * w) * 1024,     aS0 + (h) * HSTEP + (t) * 64); \
    async16(AsB + (sl) * 32768 + (h) * 16384 + (2 * w + 1) * 1024, aS1 + (h) * HSTEP + (t) * 64); \
  } while (0)
#define STG_B(sl, h, t) do { \
    async16(BsB + (sl) * 32768 + (h) * 16384 + (2 * w) * 1024,     bS0 + (h) * HSTEP + (t) * 64); \
    async16(BsB + (sl) * 32768 + (h) * 16384 + (2 * w + 1) * 1024, bS1 + (h) * HSTEP + (t) * 64); \
  } while (0)

  // fragment read: global chunk g of row r lives at LDS chunk g ^ (r&7); r&7 == lr&7
  const int cs0 = ((0 + lg) ^ (lr & 7)) * 8;  // kk=0: want chunk lg
  const int cs1 = ((4 + lg) ^ (lr & 7)) * 8;  // kk=1: want chunk 4+lg
  const _Float16* Af = (const _Float16*)AsB + wm * 8192 + lr * 64;
  const _Float16* Bf = (const _Float16*)BsB + (wn >> 1) * 8192 + ((wn & 1) * 64 + lr) * 64;

  f32x4 acc[8][4] = {};

  // prologue: tile0 (4 halves) + Ah0 of tile1; counted wait (tile0 retired, 2 in flight)
  STG_A(0, 0, 0); STG_A(0, 1, 0); STG_B(0, 0, 0); STG_B(0, 1, 0);
  STG_A(1, 0, 1);
  asm volatile("s_waitcnt vmcnt(2)" ::: "memory");
  PIN(); __builtin_amdgcn_s_barrier(); PIN();

  for (int t = 0; t < NT; ++t) {
    const int sl = t & 1;
    const int so = sl * 16384;
    half8 bf[4], af[4];

    // ---- phase 1: q0,kk0 (read B kk0) | stage Ah1(t+1)
#pragma unroll
    for (int nf = 0; nf < 4; nf++) bf[nf] = *(const half8*)(Bf + so + nf * 1024 + cs0);
#pragma unroll
    for (int m = 0; m < 4; m++) af[m] = *(const half8*)(Af + so + m * 1024 + cs0);
    if (t + 1 < NT) STG_A(sl ^ 1, 1, t + 1);
    PIN(); __builtin_amdgcn_s_barrier(); PIN();
    __builtin_amdgcn_s_setprio(1);
#pragma unroll
    for (int m = 0; m < 4; m++)
#pragma unroll
      for (int nf = 0; nf < 4; nf++)
        acc[m][nf] = __builtin_amdgcn_mfma_f32_16x16x32_f16(af[m], bf[nf], acc[m][nf], 0, 0, 0);
    __builtin_amdgcn_s_setprio(0);
    PIN(); __builtin_amdgcn_s_barrier(); PIN();

    // ---- phase 2: q1,kk0 (reuse B) | stage Bh0(t+1)
#pragma unroll
    for (int m = 0; m < 4; m++) af[m] = *(const half8*)(Af + so + (4 + m) * 1024 + cs0);
    if (t + 1 < NT) STG_B(sl ^ 1, 0, t + 1);
    PIN(); __builtin_amdgcn_s_barrier(); PIN();
    __builtin_amdgcn_s_setprio(1);
#pragma unroll
    for (int m = 0; m < 4; m++)
#pragma unroll
      for (int nf = 0; nf < 4; nf++)
        acc[4 + m][nf] = __builtin_amdgcn_mfma_f32_16x16x32_f16(af[m], bf[nf], acc[4 + m][nf], 0, 0, 0);
    __builtin_amdgcn_s_setprio(0);
    PIN(); __builtin_amdgcn_s_barrier(); PIN();

    // ---- phase 3: q0,kk1 (read B kk1) | stage Bh1(t+1)
#pragma unroll
    for (int nf = 0; nf < 4; nf++) bf[nf] = *(const half8*)(Bf + so + nf * 1024 + cs1);
#pragma unroll
    for (int m = 0; m < 4; m++) af[m] = *(const half8*)(Af + so + m * 1024 + cs1);
    if (t + 1 < NT) STG_B(sl ^ 1, 1, t + 1);
    PIN(); __builtin_amdgcn_s_barrier(); PIN();
    __builtin_amdgcn_s_setprio(1);
#pragma unroll
    for (int m = 0; m < 4; m++)
#pragma unroll
      for (int nf = 0; nf < 4; nf++)
        acc[m][nf] = __builtin_amdgcn_mfma_f32_16x16x32_f16(af[m], bf[nf], acc[m][nf], 0, 0, 0);
    __builtin_amdgcn_s_setprio(0);
    PIN(); __builtin_amdgcn_s_barrier(); PIN();

    // ---- phase 4: q1,kk1
#pragma unroll
    for (int m = 0; m < 4; m++) af[m] = *(const half8*)(Af + so + (4 + m) * 1024 + cs1);
    PIN(); __builtin_amdgcn_s_barrier(); PIN();
    __builtin_amdgcn_s_setprio(1);
#pragma unroll
    for (int m = 0; m < 4; m++)
#pragma unroll
      for (int nf = 0; nf < 4; nf++)
        acc[4 + m][nf] = __builtin_amdgcn_mfma_f32_16x16x32_f16(af[m], bf[nf], acc[4 + m][nf], 0, 0, 0);
    __builtin_amdgcn_s_setprio(0);
    // boundary: all waves done reading slot sl after this barrier
    PIN(); __builtin_amdgcn_s_barrier(); PIN();
    if (t + 2 < NT) {
      STG_A(sl, 0, t + 2);  // slot sl just freed
      asm volatile("s_waitcnt vmcnt(2)" ::: "memory");  // t+1 halves retired, t+2 in flight
    } else if (t + 1 < NT) {
      asm volatile("s_waitcnt vmcnt(0)" ::: "memory");  // final handoff only
    }
    PIN(); __builtin_amdgcn_s_barrier(); PIN();
  }

  // ---------------- epilogue (all staging drained) ----------------
  if (col0 < 4096) {  // Q frag-tiled (pre-rope)
#pragma unroll
    for (int mf = 0; mf < 8; mf++)
#pragma unroll
      for (int nf = 0; nf < 4; nf++) {
        int rbase = row0 + wm * 128 + mf * 16 + lg * 4;
        int col = col0 + wn * 64 + nf * 16 + lr;
        int h = col >> 7, d = col & 127;
        long off = ((long)((h * 128 + (rbase >> 4)) * 4 + (d >> 5))) * 512 +
                   ((d >> 3) & 3) * 128 + (rbase & 15) * 8 + (d & 7);
#pragma unroll
        for (int i = 0; i < 4; i++) Qt[off + i * 8] = (_Float16)acc[mf][nf][i];
      }
  } else if (col0 < 5120) {  // K frag-tiled + fused RoPE (wn pair exchange via overlay)
    float* fl = (float*)smem;
    float* myreg = fl + (wm * 2 + (wn >> 1)) * 8192;  // [128][64] f32
    if (wn & 1) {  // hi half (d in [64,128)): stash
#pragma unroll
      for (int mf = 0; mf < 8; mf++)
#pragma unroll
        for (int nf = 0; nf < 4; nf++)
#pragma unroll
          for (int i = 0; i < 4; i++)
            myreg[(mf * 16 + lg * 4 + i) * 64 + nf * 16 + lr] = acc[mf][nf][i];
    }
    __syncthreads();
    if (!(wn & 1)) {  // lo half: write both halves roped
      const int g = ((col0 - 4096) >> 7) + (wn >> 1);
#pragma unroll
      for (int mf = 0; mf < 8; mf++)
#pragma unroll
        for (int nf = 0; nf < 4; nf++)
#pragma unroll
          for (int i = 0; i < 4; i++) {
            int rl = mf * 16 + lg * 4 + i;
            int d = nf * 16 + lr;
            int s_glob = row0 + wm * 128 + rl;
            float lo = acc[mf][nf][i];
            float hi = myreg[rl * 64 + d];
            float c = cosb[s_glob * 128 + d];
            float sn = sinb[s_glob * 128 + d];
            long off = ((long)((g * 128 + (s_glob >> 4)) * 4 + (d >> 5))) * 512 +
                       ((d >> 3) & 3) * 128 + (s_glob & 15) * 8 + (d & 7);
            Kt[off] = (_Float16)(lo * c - hi * sn);
            Kt[off + 1024] = (_Float16)(hi * c + lo * sn);
          }
    }
  } else {  // V PV-fragment layout
#pragma unroll
    for (int mf = 0; mf < 8; mf++)
#pragma unroll
      for (int nf = 0; nf < 4; nf++) {
        int rbase = row0 + wm * 128 + mf * 16 + lg * 4;
        int col = col0 + wn * 64 + nf * 16 + lr;
        int gc = col - 5120;
        int gq = gc >> 7, d = gc & 127;
        int dt = d >> 4, lrr = d & 15;
        int kvb = rbase >> 5, lgv = (rbase >> 3) & 3, j = rbase & 7;
        half4 v;
#pragma unroll
        for (int i = 0; i < 4; i++) v[i] = (_Float16)acc[mf][nf][i];
        long off = ((long)(gq * 64 + kvb) * 8 + dt) * 512 + (lgv * 16 + lrr) * 8 + j;
        *(half4*)&Vt[off] = v;
      }
  }
#undef STG_A
#undef STG_B
}

// ---------- O-projection GEMM: [2048][4096] f16 @ [4096][4096]^T -> f32 out ----------
__global__ __launch_bounds__(256, 3) void gemm_out(
    const _Float16* __restrict__ A, const _Float16* __restrict__ Bt,
    float* __restrict__ C) {
  __shared__ _Float16 As[128 * 64];
  __shared__ _Float16 Bs[128 * 64];
  const int K = 4096;
  const int tid = threadIdx.x, lane = tid & 63, wid = tid >> 6;
  const int row0 = blockIdx.y * 128;
  const int col0 = blockIdx.x * 128;
  const int wm = wid >> 1, wn = wid & 1;
  const int lr = lane & 15, lg = lane >> 4;

  const int scol = ((lane & 7) ^ ((lane >> 3) & 7)) * 8;
  const _Float16* aptr = A + (long)(row0 + wid * 32 + (lane >> 3)) * K + scol;
  const _Float16* bptr = Bt + (long)(col0 + wid * 32 + (lane >> 3)) * K + scol;
  _Float16* alds = As + (wid * 4) * 512;
  _Float16* blds = Bs + (wid * 4) * 512;

  f32x4 acc[4][4] = {};
  for (int k0 = 0; k0 < K; k0 += 64) {
#pragma unroll
    for (int j = 0; j < 4; j++) {
      async16(alds + j * 512, aptr + k0 + (long)j * 8 * K);
      async16(blds + j * 512, bptr + k0 + (long)j * 8 * K);
    }
    __syncthreads();
    half8 a[2][4], b[2][4];
#pragma unroll
    for (int kk = 0; kk < 2; kk++)
#pragma unroll
      for (int mf = 0; mf < 4; mf++) {
        a[kk][mf] = *(const half8*)&As[(wm * 64 + mf * 16 + lr) * 64 +
                                       (((kk * 4 + lg) ^ (lr & 7)) * 8)];
        b[kk][mf] = *(const half8*)&Bs[(wn * 64 + mf * 16 + lr) * 64 +
                                       (((kk * 4 + lg) ^ (lr & 7)) * 8)];
      }
#pragma unroll
    for (int kk = 0; kk < 2; kk++)
#pragma unroll
      for (int mf = 0; mf < 4; mf++)
#pragma unroll
        for (int nf = 0; nf < 4; nf++)
          acc[mf][nf] =
              __builtin_amdgcn_mfma_f32_16x16x32_f16(a[kk][mf], b[kk][nf], acc[mf][nf], 0, 0, 0);
    __syncthreads();
  }
#pragma unroll
  for (int mf = 0; mf < 4; mf++)
#pragma unroll
    for (int nf = 0; nf < 4; nf++) {
      int rbase = row0 + wm * 64 + mf * 16 + lg * 4;
      int col = col0 + wn * 64 + nf * 16 + lr;
#pragma unroll
      for (int i = 0; i < 4; i++)
        C[(long)(rbase + i) * 4096 + col] = acc[mf][nf][i];
    }
}

// ---------- fused: causal GQA attention (bid<1024) + wo^T transpose (bid>=1024) ----------
// (256,3): do NOT tighten to (256,4) — R12 showed spills (attn 57 -> 112us).
__global__ __launch_bounds__(256, 3) void attn_wo_kernel(
    const _Float16* __restrict__ Qt, const _Float16* __restrict__ Kt,
    const _Float16* __restrict__ Vt, _Float16* __restrict__ O,
    const float* __restrict__ cosb, const float* __restrict__ sinb,
    const float* __restrict__ wo, _Float16* __restrict__ WoT) {
  __shared__ __align__(16) char smem[36864];
  const int tid = threadIdx.x;
  const int bid = blockIdx.x;  // 1024 attn + 4096 transpose

  if (bid >= 1024) {  // ---- wo^T
    int tt = bid - 1024;
    transpose_tile(wo, WoT, 4096, 4096, tt & 63, tt >> 6, (float(*)[73])smem, tid);
    return;
  }

  _Float16* Kb = (_Float16*)smem;            // [2][4096]
  _Float16* Vb = (_Float16*)(smem + 16384);  // [2][4096]
  _Float16* Pb = (_Float16*)(smem + 32768) + (tid >> 6) * 512;  // per-wave [512]

  const int lane = tid & 63;
  const int wid = tid >> 6;
  const int g = bid & 7;
  const int qidx = bid >> 3;
  const int qt16 = (qidx < 64) ? (2 * qidx) : (2 * (127 - qidx) + 1);
  const int h = g * 4 + wid;
  const int qrow0 = qt16 * 16;
  const int ntiles = (qrow0 + 47) >> 5;
  const int lr = lane & 15;
  const int lg = lane >> 4;

  // Q fragments + fused RoPE (rotate-half partner: fragment t <-> t+2, same lane)
  half8 qf[4];
  {
    const _Float16* qp = Qt + ((long)(h * 128 + qt16) * 4) * 512 + lane * 8;
#pragma unroll
    for (int t = 0; t < 4; t++) qf[t] = *(const half8*)(qp + t * 512);
    int s = qrow0 + lr;
#pragma unroll
    for (int t = 0; t < 2; t++) {
      const float* cp = cosb + s * 128 + t * 32 + lg * 8;
      const float* sp = sinb + s * 128 + t * 32 + lg * 8;
#pragma unroll
      for (int j = 0; j < 8; j++) {
        float c = cp[j], sn = sp[j];
        float lo = (float)qf[t][j], hi = (float)qf[t + 2][j];
        qf[t][j]     = (_Float16)(lo * c - hi * sn);
        qf[t + 2][j] = (_Float16)(hi * c + lo * sn);
      }
    }
  }

  const _Float16* kgb = Kt + (long)g * 128 * 2048 + lane * 8;
  const _Float16* vgb = Vt + (long)g * 64 * 4096 + lane * 8;

  {
    async16(&Kb[(2 * wid) * 512], kgb + (2 * wid) * 512);
    async16(&Kb[(2 * wid + 1) * 512], kgb + (2 * wid + 1) * 512);
    async16(&Vb[(2 * wid) * 512], vgb + (2 * wid) * 512);
    async16(&Vb[(2 * wid + 1) * 512], vgb + (2 * wid + 1) * 512);
  }
  __syncthreads();

  f32x4 oacc[8] = {};
  float mrow[4] = {-1e30f, -1e30f, -1e30f, -1e30f};
  float lsum[4] = {0.f, 0.f, 0.f, 0.f};

  for (int t = 0; t < ntiles; t++) {
    const int kb = t * 32;
    const int cur = t & 1;
    if (t + 1 < ntiles) {
      const _Float16* ks = kgb + (long)(t + 1) * 4096;
      const _Float16* vs = vgb + (long)(t + 1) * 4096;
      async16(&Kb[(cur ^ 1) * 4096 + (2 * wid) * 512], ks + (2 * wid) * 512);
      async16(&Kb[(cur ^ 1) * 4096 + (2 * wid + 1) * 512], ks + (2 * wid + 1) * 512);
      async16(&Vb[(cur ^ 1) * 4096 + (2 * wid) * 512], vs + (2 * wid) * 512);
      async16(&Vb[(cur ^ 1) * 4096 + (2 * wid + 1) * 512], vs + (2 * wid + 1) * 512);
    }

    half8 kf[8];
#pragma unroll
    for (int c = 0; c < 8; c++)
      kf[c] = *(const half8*)&Kb[cur * 4096 + c * 512 + lane * 8];
    half8 vf[8];
#pragma unroll
    for (int dt = 0; dt < 8; dt++)
      vf[dt] = *(const half8*)&Vb[cur * 4096 + dt * 512 + lane * 8];

    f32x4 sacc[2] = {};
    __builtin_amdgcn_s_setprio(1);
#pragma unroll
    for (int s = 0; s < 2; s++)
#pragma unroll
      for (int t2 = 0; t2 < 4; t2++)
        sacc[s] = __builtin_amdgcn_mfma_f32_16x16x32_f16(qf[t2], kf[s * 4 + t2], sacc[s], 0, 0, 0);
    __builtin_amdgcn_s_setprio(0);

#pragma unroll
    for (int i = 0; i < 4; i++) {
      sacc[0][i] *= SCALE_QK;
      sacc[1][i] *= SCALE_QK;
    }
    if (t == ntiles - 1) {  // only the last tile can touch the diagonal
#pragma unroll
      for (int i = 0; i < 4; i++) {
        int qrow = qrow0 + lg * 4 + i;
        if (kb + lr > qrow) sacc[0][i] = -1e30f;
        if (kb + 16 + lr > qrow) sacc[1][i] = -1e30f;
      }
    }
    float mx[4];
    bool grow = false;
#pragma unroll
    for (int i = 0; i < 4; i++) {
      mx[i] = fmaxf(sacc[0][i], sacc[1][i]);
      grow |= (mx[i] > mrow[i] + 4.0f);
    }
    if (__any((int)grow)) {
#pragma unroll
      for (int i = 0; i < 4; i++) {
        float m = mx[i];
        m = fmaxf(m, __shfl_xor(m, 1));
        m = fmaxf(m, __shfl_xor(m, 2));
        m = fmaxf(m, __shfl_xor(m, 4));
        m = fmaxf(m, __shfl_xor(m, 8));
        float mn = fmaxf(mrow[i], m);
        float scl = __expf(mrow[i] - mn);
        mrow[i] = mn;
        lsum[i] *= scl;
#pragma unroll
        for (int dt = 0; dt < 8; dt++) oacc[dt][i] *= scl;
      }
    }
    float p[2][4];
#pragma unroll
    for (int i = 0; i < 4; i++) {
      p[0][i] = __expf(sacc[0][i] - mrow[i]);
      p[1][i] = __expf(sacc[1][i] - mrow[i]);
      lsum[i] += p[0][i] + p[1][i];
    }

#pragma unroll
    for (int sub = 0; sub < 2; sub++)
#pragma unroll
      for (int i = 0; i < 4; i++)
        Pb[(lg * 4 + i) * 32 + sub * 16 + lr] = (_Float16)p[sub][i];
    half8 pa = *(const half8*)&Pb[lr * 32 + lg * 8];

    __builtin_amdgcn_s_setprio(1);
#pragma unroll
    for (int dt = 0; dt < 8; dt++)
      oacc[dt] = __builtin_amdgcn_mfma_f32_16x16x32_f16(pa, vf[dt], oacc[dt], 0, 0, 0);
    __builtin_amdgcn_s_setprio(0);

    __syncthreads();
  }

#pragma unroll
  for (int i = 0; i < 4; i++) {
    float t2 = lsum[i];
    t2 += __shfl_xor(t2, 1);
    t2 += __shfl_xor(t2, 2);
    t2 += __shfl_xor(t2, 4);
    t2 += __shfl_xor(t2, 8);
    lsum[i] = t2;
  }
#pragma unroll
  for (int dt = 0; dt < 8; dt++) {
#pragma unroll
    for (int i = 0; i < 4; i++) {
      float o = oacc[dt][i] / lsum[i];
      O[(long)(qrow0 + lg * 4 + i) * HID_DIM + h * HEAD_DIM + dt * 16 + lr] = (_Float16)o;
    }
  }
}

extern "C" void kernel_launch(void* const* d_in, const int* in_sizes, int n_in,
                              void* d_out, int out_size, void* d_ws, size_t ws_size,
                              hipStream_t stream) {
  const float* x    = (const float*)d_in[0];
  const float* cosb = (const float*)d_in[1];
  const float* sinb = (const float*)d_in[2];
  // d_in[3] = attn_mask: pure causal, implemented in-kernel
  const float* wq = (const float*)d_in[4];
  const float* wk = (const float*)d_in[5];
  const float* wv = (const float*)d_in[6];
  const float* wo = (const float*)d_in[7];
  float* out = (float*)d_out;

  char* ws = (char*)d_ws;
  _Float16* Xh    = (_Float16*)(ws);                        // [0,16M): X f16; later Oattn
  _Float16* Oattn = Xh;
  _Float16* Qt    = (_Float16*)(ws + (size_t)(16 << 20));   // [16,32M): Q frag-tiled (pre-rope)
  _Float16* Kt    = (_Float16*)(ws + (size_t)(32 << 20));   // [32,36M): K frag-tiled (roped)
  _Float16* Vt    = (_Float16*)(ws + (size_t)(36 << 20));   // [36,40M): V PV-tiled
  _Float16* WqT   = (_Float16*)(ws + (size_t)(40 << 20));   // [40,72M): wq^T, later wo^T
  _Float16* WoT   = WqT;
  _Float16* WkvT  = (_Float16*)d_out;                       // 16MB scratch in d_out
  // peak ws usage: 72 MiB

  dim3 b256(256);

  // merged prep: X->f16 + wq^T + wk^T + wv^T (one dispatch, 10240 blocks)
  prep_kernel<<<dim3(10240), b256, 0, stream>>>(x, Xh, wq, WqT, wk, wv, WkvT);

  // 8-phase 256^2 QKV projection (N=6144: 24x8 = 192 blocks, 1/CU), fused K-RoPE
  gemm_qkv8<<<dim3(6144 / 256, S_LEN / 256), dim3(512), 0, stream>>>(
      Xh, WqT, WkvT, Qt, Kt, Vt, cosb, sinb);

  // fused: causal GQA attention (+Q-RoPE) -> Oattn, with wo^T hidden underneath
  attn_wo_kernel<<<dim3(1024 + 4096), b256, 0, stream>>>(Qt, Kt, Vt, Oattn, cosb, sinb, wo, WoT);

  // out = Oattn @ Wo (f32)
  gemm_out<<<dim3(4096 / 128, S_LEN / 128), b256, 0, stream>>>(Oattn, WoT, out);
}